// Round 4
// baseline (159.250 us; speedup 1.0000x reference)
//
#include <hip/hip_runtime.h>

#define N_FEAT 2048
#define ORDER 8
#define BATCH 8192
#define BLOCK 256
#define ROWS 4          // batch rows per block
#define NPAIR 28        // ORDER*(ORDER-1)/2

typedef float v4f __attribute__((ext_vector_type(4)));

__device__ __forceinline__ float dot4(v4f a, v4f b) {
    return a.x * b.x + a.y * b.y + a.z * b.z + a.w * b.w;
}

// ---- prep (1 block): normalize v -> vn, build compact-WY T (8x8) ----------
// H0*H1*...*H7 = I - V T V^T ; T_{k+1} = [[T_k, -2 T_k g],[0,2]], g_j = vj.vk
__global__ __launch_bounds__(BLOCK) void prep_kernel(
    const float* __restrict__ v, float* __restrict__ vn,
    float* __restrict__ Tm) {
    const int tid = threadIdx.x;
    const int lane = tid & 63, wid = tid >> 6;

    v4f a0[ORDER], a1[ORDER];
    #pragma unroll
    for (int i = 0; i < ORDER; ++i) {
        a0[i] = *(const v4f*)(v + (size_t)i * N_FEAT + tid * 4);
        a1[i] = *(const v4f*)(v + (size_t)i * N_FEAT + 1024 + tid * 4);
    }
    float ss[ORDER];
    #pragma unroll
    for (int i = 0; i < ORDER; ++i)
        ss[i] = dot4(a0[i], a0[i]) + dot4(a1[i], a1[i]);
    #pragma unroll
    for (int o = 32; o > 0; o >>= 1)
        #pragma unroll
        for (int i = 0; i < ORDER; ++i) ss[i] += __shfl_down(ss[i], o, 64);

    __shared__ float red[4][ORDER];
    __shared__ float gred[4][NPAIR];
    if (lane == 0) {
        #pragma unroll
        for (int i = 0; i < ORDER; ++i) red[wid][i] = ss[i];
    }
    __syncthreads();
    #pragma unroll
    for (int i = 0; i < ORDER; ++i) {
        const float inv = 1.0f / sqrtf(red[0][i] + red[1][i] + red[2][i] + red[3][i]);
        a0[i] *= inv; a1[i] *= inv;
        *(v4f*)(vn + (size_t)i * N_FEAT + tid * 4) = a0[i];
        *(v4f*)(vn + (size_t)i * N_FEAT + 1024 + tid * 4) = a1[i];
    }

    float gp[NPAIR];
    {
        int idx = 0;
        #pragma unroll
        for (int j = 0; j < ORDER; ++j)
            #pragma unroll
            for (int k = j + 1; k < ORDER; ++k)
                gp[idx++] = dot4(a0[j], a0[k]) + dot4(a1[j], a1[k]);
    }
    #pragma unroll
    for (int o = 32; o > 0; o >>= 1)
        #pragma unroll
        for (int q = 0; q < NPAIR; ++q) gp[q] += __shfl_down(gp[q], o, 64);
    if (lane == 0) {
        #pragma unroll
        for (int q = 0; q < NPAIR; ++q) gred[wid][q] = gp[q];
    }
    __syncthreads();

    if (tid == 0) {
        float G[ORDER][ORDER];
        {
            int idx = 0;
            #pragma unroll
            for (int j = 0; j < ORDER; ++j)
                #pragma unroll
                for (int k = j + 1; k < ORDER; ++k) {
                    G[j][k] = gred[0][idx] + gred[1][idx] + gred[2][idx] + gred[3][idx];
                    ++idx;
                }
        }
        float T[ORDER][ORDER];
        #pragma unroll
        for (int j = 0; j < ORDER; ++j)
            #pragma unroll
            for (int k = 0; k < ORDER; ++k) T[j][k] = 0.0f;
        T[0][0] = 2.0f;
        #pragma unroll
        for (int k = 1; k < ORDER; ++k) {
            #pragma unroll
            for (int j = 0; j < k; ++j) {
                float s = 0.0f;
                #pragma unroll
                for (int m = j; m < k; ++m) s += T[j][m] * G[m][k];
                T[j][k] = -2.0f * s;
            }
            T[k][k] = 2.0f;
        }
        #pragma unroll
        for (int j = 0; j < ORDER; ++j)
            #pragma unroll
            for (int k = 0; k < ORDER; ++k)
                Tm[j * ORDER + k] = T[j][k];
    }
}

// ---- apply: y = (x - (x V) T V^T) * d + bias -------------------------------
// One-pass, z-persistent, vn-IN-REGISTERS (16 v4f loaded once per thread,
// reused by projection AND update). Minimal operand traffic (vn read once
// per block = 0.5 MB/CU); after the single barrier the update is pure
// register FMA — no memory on the post-barrier critical path.
// Plain (cached) y stores this round: nt-store throughput is the fixed-cost
// suspect shared by all previous variants.
__global__ __launch_bounds__(BLOCK, 3) void orth_apply_kernel(
    const float* __restrict__ x, const float* __restrict__ vn,
    const float* __restrict__ Tm, const float* __restrict__ d,
    const float* __restrict__ bias, float* __restrict__ y) {
    const int tid = threadIdx.x;
    const int lane = tid & 63, wid = tid >> 6;
    const size_t base = (size_t)blockIdx.x * ROWS * N_FEAT;
    const int c0 = tid * 4;
    const int c1 = 1024 + tid * 4;

    // vn fragments: loaded ONCE, live for the whole kernel (64 VGPR).
    v4f a0[ORDER], a1[ORDER];
    #pragma unroll
    for (int i = 0; i < ORDER; ++i) {
        a0[i] = *(const v4f*)(vn + (size_t)i * N_FEAT + c0);
        a1[i] = *(const v4f*)(vn + (size_t)i * N_FEAT + c1);
    }

    // x: read once, nt (don't pollute caches that hold vn).
    v4f z0[ROWS], z1[ROWS];
    #pragma unroll
    for (int r = 0; r < ROWS; ++r) {
        z0[r] = __builtin_nontemporal_load((const v4f*)(x + base + (size_t)r * N_FEAT + c0));
        z1[r] = __builtin_nontemporal_load((const v4f*)(x + base + (size_t)r * N_FEAT + c1));
    }

    // Phase 1: all 32 projections (4 rows x 8 vectors), full ILP.
    float p[ROWS][ORDER];
    #pragma unroll
    for (int i = 0; i < ORDER; ++i)
        #pragma unroll
        for (int r = 0; r < ROWS; ++r)
            p[r][i] = dot4(z0[r], a0[i]) + dot4(z1[r], a1[i]);

    #pragma unroll
    for (int o = 32; o > 0; o >>= 1)
        #pragma unroll
        for (int r = 0; r < ROWS; ++r)
            #pragma unroll
            for (int i = 0; i < ORDER; ++i)
                p[r][i] += __shfl_down(p[r][i], o, 64);

    // Packed cross-wave combine: b128 writes/reads, one barrier.
    __shared__ v4f red[4][ROWS][2];
    if (lane == 0) {
        #pragma unroll
        for (int r = 0; r < ROWS; ++r) {
            v4f lo, hi;
            lo.x = p[r][0]; lo.y = p[r][1]; lo.z = p[r][2]; lo.w = p[r][3];
            hi.x = p[r][4]; hi.y = p[r][5]; hi.z = p[r][6]; hi.w = p[r][7];
            red[wid][r][0] = lo;
            red[wid][r][1] = hi;
        }
    }
    __syncthreads();   // the ONLY barrier

    v4f ps[ROWS][2];
    #pragma unroll
    for (int r = 0; r < ROWS; ++r) {
        ps[r][0] = (red[0][r][0] + red[1][r][0]) + (red[2][r][0] + red[3][r][0]);
        ps[r][1] = (red[0][r][1] + red[1][r][1]) + (red[2][r][1] + red[3][r][1]);
    }

    // c = p @ T (T upper-triangular, wave-uniform -> s_loads)
    float c[ROWS][ORDER];
    #pragma unroll
    for (int i = 0; i < ORDER; ++i)
        #pragma unroll
        for (int r = 0; r < ROWS; ++r) {
            float s = 0.0f;
            #pragma unroll
            for (int j = 0; j <= i; ++j)
                s += ps[r][j >> 2][j & 3] * Tm[j * ORDER + i];
            c[r][i] = s;
        }

    // Phase 2: z -= sum_i c_i * v_i — pure register FMA, zero memory ops.
    #pragma unroll
    for (int i = 0; i < ORDER; ++i)
        #pragma unroll
        for (int r = 0; r < ROWS; ++r) {
            z0[r] -= c[r][i] * a0[i];
            z1[r] -= c[r][i] * a1[i];
        }

    // Epilogue: y = z * d + bias, PLAIN stores (nt-store throughput test).
    const v4f d0 = *(const v4f*)(d + c0);
    const v4f d1 = *(const v4f*)(d + c1);
    const v4f b0 = *(const v4f*)(bias + c0);
    const v4f b1 = *(const v4f*)(bias + c1);
    #pragma unroll
    for (int r = 0; r < ROWS; ++r) {
        v4f o0 = z0[r] * d0 + b0;
        v4f o1 = z1[r] * d1 + b1;
        *(v4f*)(y + base + (size_t)r * N_FEAT + c0) = o0;
        *(v4f*)(y + base + (size_t)r * N_FEAT + c1) = o1;
    }
}

extern "C" void kernel_launch(void* const* d_in, const int* in_sizes, int n_in,
                              void* d_out, int out_size, void* d_ws, size_t ws_size,
                              hipStream_t stream) {
    const float* x    = (const float*)d_in[0];  // [8192, 2048]
    const float* v    = (const float*)d_in[1];  // [8, 2048]
    const float* d    = (const float*)d_in[2];  // [2048]
    const float* bias = (const float*)d_in[3];  // [2048]
    float* y  = (float*)d_out;                  // [8192, 2048]
    float* vn = (float*)d_ws;                   // [8, 2048] normalized vectors
    float* Tm = vn + ORDER * N_FEAT;            // [8, 8] WY T-factor

    prep_kernel<<<1, BLOCK, 0, stream>>>(v, vn, Tm);
    orth_apply_kernel<<<BATCH / ROWS, BLOCK, 0, stream>>>(x, vn, Tm, d, bias, y);
}

// Round 5
// 136.825 us; speedup vs baseline: 1.1639x; 1.1639x over previous
//
#include <hip/hip_runtime.h>

#define N_FEAT 2048
#define ORDER 8
#define BATCH 8192
#define BLOCK 256
#define ROWS 4          // batch rows per block
#define NPAIR 28        // ORDER*(ORDER-1)/2
#define NVAL 32         // ROWS*ORDER reduction values per block

typedef float v4f __attribute__((ext_vector_type(4)));

__device__ __forceinline__ float dot4(v4f a, v4f b) {
    return a.x * b.x + a.y * b.y + a.z * b.z + a.w * b.w;
}

// ---- prep (1 block): normalize v -> vn, build compact-WY T (8x8) ----------
// H0*H1*...*H7 = I - V T V^T ; T_{k+1} = [[T_k, -2 T_k g],[0,2]], g_j = vj.vk
__global__ __launch_bounds__(BLOCK) void prep_kernel(
    const float* __restrict__ v, float* __restrict__ vn,
    float* __restrict__ Tm) {
    const int tid = threadIdx.x;
    const int lane = tid & 63, wid = tid >> 6;

    v4f a0[ORDER], a1[ORDER];
    #pragma unroll
    for (int i = 0; i < ORDER; ++i) {
        a0[i] = *(const v4f*)(v + (size_t)i * N_FEAT + tid * 4);
        a1[i] = *(const v4f*)(v + (size_t)i * N_FEAT + 1024 + tid * 4);
    }
    float ss[ORDER];
    #pragma unroll
    for (int i = 0; i < ORDER; ++i)
        ss[i] = dot4(a0[i], a0[i]) + dot4(a1[i], a1[i]);
    #pragma unroll
    for (int o = 32; o > 0; o >>= 1)
        #pragma unroll
        for (int i = 0; i < ORDER; ++i) ss[i] += __shfl_down(ss[i], o, 64);

    __shared__ float red[4][ORDER];
    __shared__ float gred[4][NPAIR];
    if (lane == 0) {
        #pragma unroll
        for (int i = 0; i < ORDER; ++i) red[wid][i] = ss[i];
    }
    __syncthreads();
    #pragma unroll
    for (int i = 0; i < ORDER; ++i) {
        const float inv = 1.0f / sqrtf(red[0][i] + red[1][i] + red[2][i] + red[3][i]);
        a0[i] *= inv; a1[i] *= inv;
        *(v4f*)(vn + (size_t)i * N_FEAT + tid * 4) = a0[i];
        *(v4f*)(vn + (size_t)i * N_FEAT + 1024 + tid * 4) = a1[i];
    }

    float gp[NPAIR];
    {
        int idx = 0;
        #pragma unroll
        for (int j = 0; j < ORDER; ++j)
            #pragma unroll
            for (int k = j + 1; k < ORDER; ++k)
                gp[idx++] = dot4(a0[j], a0[k]) + dot4(a1[j], a1[k]);
    }
    #pragma unroll
    for (int o = 32; o > 0; o >>= 1)
        #pragma unroll
        for (int q = 0; q < NPAIR; ++q) gp[q] += __shfl_down(gp[q], o, 64);
    if (lane == 0) {
        #pragma unroll
        for (int q = 0; q < NPAIR; ++q) gred[wid][q] = gp[q];
    }
    __syncthreads();

    if (tid == 0) {
        float G[ORDER][ORDER];
        {
            int idx = 0;
            #pragma unroll
            for (int j = 0; j < ORDER; ++j)
                #pragma unroll
                for (int k = j + 1; k < ORDER; ++k) {
                    G[j][k] = gred[0][idx] + gred[1][idx] + gred[2][idx] + gred[3][idx];
                    ++idx;
                }
        }
        float T[ORDER][ORDER];
        #pragma unroll
        for (int j = 0; j < ORDER; ++j)
            #pragma unroll
            for (int k = 0; k < ORDER; ++k) T[j][k] = 0.0f;
        T[0][0] = 2.0f;
        #pragma unroll
        for (int k = 1; k < ORDER; ++k) {
            #pragma unroll
            for (int j = 0; j < k; ++j) {
                float s = 0.0f;
                #pragma unroll
                for (int m = j; m < k; ++m) s += T[j][m] * G[m][k];
                T[j][k] = -2.0f * s;
            }
            T[k][k] = 2.0f;
        }
        #pragma unroll
        for (int j = 0; j < ORDER; ++j)
            #pragma unroll
            for (int k = 0; k < ORDER; ++k)
                Tm[j * ORDER + k] = T[j][k];
    }
}

// ---- apply: y = (x - (x V) T V^T) * d + bias -------------------------------
// One-pass, z-persistent. Reduction = multi-value PACKING butterfly:
// 31 shuffles for all 32 values (vs 192 for the naive per-value butterfly),
// then one wave-wide ds_add_f32 into a 32-float LDS array, one barrier,
// 8 broadcast b128 reads. DS ops/thread: ~232 -> ~41.
__global__ __launch_bounds__(BLOCK, 3) void orth_apply_kernel(
    const float* __restrict__ x, const float* __restrict__ vn,
    const float* __restrict__ Tm, const float* __restrict__ d,
    const float* __restrict__ bias, float* __restrict__ y) {
    const int tid = threadIdx.x;
    const int lane = tid & 63;
    const size_t base = (size_t)blockIdx.x * ROWS * N_FEAT;
    const int c0 = tid * 4;
    const int c1 = 1024 + tid * 4;

    __shared__ v4f S4[NVAL / 4];
    float* Sf = (float*)S4;
    if (tid < NVAL) Sf[tid] = 0.0f;
    __syncthreads();   // zeros visible before any ds_add below

    // vn fragments: loaded once (compiler may cache in regs or reload from L1).
    v4f a0[ORDER], a1[ORDER];
    #pragma unroll
    for (int i = 0; i < ORDER; ++i) {
        a0[i] = *(const v4f*)(vn + (size_t)i * N_FEAT + c0);
        a1[i] = *(const v4f*)(vn + (size_t)i * N_FEAT + c1);
    }

    // x: read once, nontemporal (read-once data, keep caches for vn).
    v4f z0[ROWS], z1[ROWS];
    #pragma unroll
    for (int r = 0; r < ROWS; ++r) {
        z0[r] = __builtin_nontemporal_load((const v4f*)(x + base + (size_t)r * N_FEAT + c0));
        z1[r] = __builtin_nontemporal_load((const v4f*)(x + base + (size_t)r * N_FEAT + c1));
    }

    // Phase 1: 32 projections, flat index q = r*8 + i.
    float s[NVAL];
    #pragma unroll
    for (int i = 0; i < ORDER; ++i)
        #pragma unroll
        for (int r = 0; r < ROWS; ++r)
            s[r * ORDER + i] = dot4(z0[r], a0[i]) + dot4(z1[r], a1[i]);

    // Packing reduction: step with mask m merges value pairs (2j, 2j+1);
    // even value -> lanes with bit m = 0, odd -> bit m = 1. After 5 steps
    // lane l holds the 32-lane partial of value (l & 31); lanes l and l+32
    // hold complementary halves (both are added below, completing the sum).
    #pragma unroll
    for (int step = 0; step < 5; ++step) {
        const int m = 1 << step;
        const int n = NVAL >> step;
        #pragma unroll
        for (int j = 0; j < n / 2; ++j) {
            const float a = s[2 * j], b = s[2 * j + 1];
            const float keep = (lane & m) ? b : a;
            const float send = (lane & m) ? a : b;
            s[j] = keep + __shfl_xor(send, m, 64);
        }
    }

    // Cross-wave + cross-half combine: one ds_add_f32 per thread.
    atomicAdd(&Sf[lane & (NVAL - 1)], s[0]);
    __syncthreads();   // all partials landed

    // Broadcast read of the 32 finished sums (8x b128, same-address bcast).
    v4f Sv[NVAL / 4];
    #pragma unroll
    for (int k = 0; k < NVAL / 4; ++k) Sv[k] = S4[k];
    #define PVAL(r, j) (Sv[((r) * ORDER + (j)) >> 2][((r) * ORDER + (j)) & 3])

    // c = p @ T (T upper-triangular, wave-uniform -> scalar loads)
    float c[ROWS][ORDER];
    #pragma unroll
    for (int i = 0; i < ORDER; ++i)
        #pragma unroll
        for (int r = 0; r < ROWS; ++r) {
            float acc = 0.0f;
            #pragma unroll
            for (int j = 0; j <= i; ++j)
                acc += PVAL(r, j) * Tm[j * ORDER + i];
            c[r][i] = acc;
        }

    // Phase 2: z -= sum_i c_i * v_i — pure register FMA.
    #pragma unroll
    for (int i = 0; i < ORDER; ++i)
        #pragma unroll
        for (int r = 0; r < ROWS; ++r) {
            z0[r] -= c[r][i] * a0[i];
            z1[r] -= c[r][i] * a1[i];
        }

    // Epilogue: y = z * d + bias, NONTEMPORAL stores (r4: plain stores
    // caused +45 MB HBM writes / +18 MB fetch and a 24 us regression).
    const v4f d0 = *(const v4f*)(d + c0);
    const v4f d1 = *(const v4f*)(d + c1);
    const v4f b0 = *(const v4f*)(bias + c0);
    const v4f b1 = *(const v4f*)(bias + c1);
    #pragma unroll
    for (int r = 0; r < ROWS; ++r) {
        v4f o0 = z0[r] * d0 + b0;
        v4f o1 = z1[r] * d1 + b1;
        __builtin_nontemporal_store(o0, (v4f*)(y + base + (size_t)r * N_FEAT + c0));
        __builtin_nontemporal_store(o1, (v4f*)(y + base + (size_t)r * N_FEAT + c1));
    }
}

extern "C" void kernel_launch(void* const* d_in, const int* in_sizes, int n_in,
                              void* d_out, int out_size, void* d_ws, size_t ws_size,
                              hipStream_t stream) {
    const float* x    = (const float*)d_in[0];  // [8192, 2048]
    const float* v    = (const float*)d_in[1];  // [8, 2048]
    const float* d    = (const float*)d_in[2];  // [2048]
    const float* bias = (const float*)d_in[3];  // [2048]
    float* y  = (float*)d_out;                  // [8192, 2048]
    float* vn = (float*)d_ws;                   // [8, 2048] normalized vectors
    float* Tm = vn + ORDER * N_FEAT;            // [8, 8] WY T-factor

    prep_kernel<<<1, BLOCK, 0, stream>>>(v, vn, Tm);
    orth_apply_kernel<<<BATCH / ROWS, BLOCK, 0, stream>>>(x, vn, Tm, d, bias, y);
}

// Round 6
// 136.064 us; speedup vs baseline: 1.1704x; 1.0056x over previous
//
#include <hip/hip_runtime.h>

#define N_FEAT 2048
#define ORDER 8
#define BATCH 8192
#define BLOCK 256
#define ROWS 4          // batch rows per block
#define NPAIR 28        // ORDER*(ORDER-1)/2
#define NVAL 32         // ROWS*ORDER reduction values per block

typedef float v4f __attribute__((ext_vector_type(4)));

__device__ __forceinline__ float dot4(v4f a, v4f b) {
    return a.x * b.x + a.y * b.y + a.z * b.z + a.w * b.w;
}

// ---- prep (1 block): normalize v -> vn, build compact-WY T (8x8) ----------
// H0*H1*...*H7 = I - V T V^T ; T_{k+1} = [[T_k, -2 T_k g],[0,2]], g_j = vj.vk
__global__ __launch_bounds__(BLOCK) void prep_kernel(
    const float* __restrict__ v, float* __restrict__ vn,
    float* __restrict__ Tm) {
    const int tid = threadIdx.x;
    const int lane = tid & 63, wid = tid >> 6;

    v4f a0[ORDER], a1[ORDER];
    #pragma unroll
    for (int i = 0; i < ORDER; ++i) {
        a0[i] = *(const v4f*)(v + (size_t)i * N_FEAT + tid * 4);
        a1[i] = *(const v4f*)(v + (size_t)i * N_FEAT + 1024 + tid * 4);
    }
    float ss[ORDER];
    #pragma unroll
    for (int i = 0; i < ORDER; ++i)
        ss[i] = dot4(a0[i], a0[i]) + dot4(a1[i], a1[i]);
    #pragma unroll
    for (int o = 32; o > 0; o >>= 1)
        #pragma unroll
        for (int i = 0; i < ORDER; ++i) ss[i] += __shfl_down(ss[i], o, 64);

    __shared__ float red[4][ORDER];
    __shared__ float gred[4][NPAIR];
    if (lane == 0) {
        #pragma unroll
        for (int i = 0; i < ORDER; ++i) red[wid][i] = ss[i];
    }
    __syncthreads();
    #pragma unroll
    for (int i = 0; i < ORDER; ++i) {
        const float inv = 1.0f / sqrtf(red[0][i] + red[1][i] + red[2][i] + red[3][i]);
        a0[i] *= inv; a1[i] *= inv;
        *(v4f*)(vn + (size_t)i * N_FEAT + tid * 4) = a0[i];
        *(v4f*)(vn + (size_t)i * N_FEAT + 1024 + tid * 4) = a1[i];
    }

    float gp[NPAIR];
    {
        int idx = 0;
        #pragma unroll
        for (int j = 0; j < ORDER; ++j)
            #pragma unroll
            for (int k = j + 1; k < ORDER; ++k)
                gp[idx++] = dot4(a0[j], a0[k]) + dot4(a1[j], a1[k]);
    }
    #pragma unroll
    for (int o = 32; o > 0; o >>= 1)
        #pragma unroll
        for (int q = 0; q < NPAIR; ++q) gp[q] += __shfl_down(gp[q], o, 64);
    if (lane == 0) {
        #pragma unroll
        for (int q = 0; q < NPAIR; ++q) gred[wid][q] = gp[q];
    }
    __syncthreads();

    if (tid == 0) {
        float G[ORDER][ORDER];
        {
            int idx = 0;
            #pragma unroll
            for (int j = 0; j < ORDER; ++j)
                #pragma unroll
                for (int k = j + 1; k < ORDER; ++k) {
                    G[j][k] = gred[0][idx] + gred[1][idx] + gred[2][idx] + gred[3][idx];
                    ++idx;
                }
        }
        float T[ORDER][ORDER];
        #pragma unroll
        for (int j = 0; j < ORDER; ++j)
            #pragma unroll
            for (int k = 0; k < ORDER; ++k) T[j][k] = 0.0f;
        T[0][0] = 2.0f;
        #pragma unroll
        for (int k = 1; k < ORDER; ++k) {
            #pragma unroll
            for (int j = 0; j < k; ++j) {
                float s = 0.0f;
                #pragma unroll
                for (int m = j; m < k; ++m) s += T[j][m] * G[m][k];
                T[j][k] = -2.0f * s;
            }
            T[k][k] = 2.0f;
        }
        #pragma unroll
        for (int j = 0; j < ORDER; ++j)
            #pragma unroll
            for (int k = 0; k < ORDER; ++k)
                Tm[j * ORDER + k] = T[j][k];
    }
}

// ---- K1: c = (x . V) T  — reduction only, retires immediately after a
// 128B/block store. x loads CACHED (primes L3/L2 for K2's re-read).
__global__ __launch_bounds__(BLOCK, 3) void proj_kernel(
    const float* __restrict__ x, const float* __restrict__ vn,
    const float* __restrict__ Tm, float* __restrict__ cbuf) {
    const int tid = threadIdx.x;
    const int lane = tid & 63;
    const size_t base = (size_t)blockIdx.x * ROWS * N_FEAT;
    const int c0 = tid * 4;
    const int c1 = 1024 + tid * 4;

    __shared__ float Sf[NVAL];
    if (tid < NVAL) Sf[tid] = 0.0f;
    __syncthreads();

    v4f a0[ORDER], a1[ORDER];
    #pragma unroll
    for (int i = 0; i < ORDER; ++i) {
        a0[i] = *(const v4f*)(vn + (size_t)i * N_FEAT + c0);
        a1[i] = *(const v4f*)(vn + (size_t)i * N_FEAT + c1);
    }
    v4f z0[ROWS], z1[ROWS];
    #pragma unroll
    for (int r = 0; r < ROWS; ++r) {
        z0[r] = *(const v4f*)(x + base + (size_t)r * N_FEAT + c0);
        z1[r] = *(const v4f*)(x + base + (size_t)r * N_FEAT + c1);
    }

    float s[NVAL];
    #pragma unroll
    for (int i = 0; i < ORDER; ++i)
        #pragma unroll
        for (int r = 0; r < ROWS; ++r)
            s[r * ORDER + i] = dot4(z0[r], a0[i]) + dot4(z1[r], a1[i]);

    // Packing reduction (r5-verified): after 5 steps lane l holds the 32-lane
    // partial of value (l&31); lanes l and l+32 are complementary halves.
    #pragma unroll
    for (int step = 0; step < 5; ++step) {
        const int m = 1 << step;
        const int n = NVAL >> step;
        #pragma unroll
        for (int j = 0; j < n / 2; ++j) {
            const float a = s[2 * j], b = s[2 * j + 1];
            const float keep = (lane & m) ? b : a;
            const float send = (lane & m) ? a : b;
            s[j] = keep + __shfl_xor(send, m, 64);
        }
    }
    atomicAdd(&Sf[lane & (NVAL - 1)], s[0]);
    __syncthreads();

    // c[r][i] = sum_{j<=i} P[r][j] * T[j][i]; one thread per output.
    if (tid < NVAL) {
        const int r = tid >> 3, i = tid & 7;
        float acc = 0.0f;
        #pragma unroll
        for (int j = 0; j < ORDER; ++j)
            if (j <= i) acc += Sf[r * ORDER + j] * Tm[j * ORDER + i];
        cbuf[((size_t)blockIdx.x * ROWS + r) * ORDER + i] = acc;
    }
}

// ---- K2: y = (x - c . V^T) * d + bias — PURE STREAMING.
// No shuffles, no barriers, no LDS. c rows are block-uniform -> scalar loads.
__global__ __launch_bounds__(BLOCK, 4) void finish_kernel(
    const float* __restrict__ x, const float* __restrict__ vn,
    const float* __restrict__ cbuf, const float* __restrict__ d,
    const float* __restrict__ bias, float* __restrict__ y) {
    const int tid = threadIdx.x;
    const size_t base = (size_t)blockIdx.x * ROWS * N_FEAT;
    const int c0 = tid * 4;
    const int c1 = 1024 + tid * 4;

    // x first: longest-latency loads get the most overlap (nt: last use).
    v4f x0[ROWS], x1[ROWS];
    #pragma unroll
    for (int r = 0; r < ROWS; ++r) {
        x0[r] = __builtin_nontemporal_load((const v4f*)(x + base + (size_t)r * N_FEAT + c0));
        x1[r] = __builtin_nontemporal_load((const v4f*)(x + base + (size_t)r * N_FEAT + c1));
    }

    // c: thread-invariant addresses -> SGPR loads.
    float c[ROWS][ORDER];
    #pragma unroll
    for (int r = 0; r < ROWS; ++r)
        #pragma unroll
        for (int i = 0; i < ORDER; ++i)
            c[r][i] = cbuf[((size_t)blockIdx.x * ROWS + r) * ORDER + i];

    // acc = sum_i c_i * v_i, vn loads interleaved with FMA.
    v4f acc0[ROWS], acc1[ROWS];
    #pragma unroll
    for (int r = 0; r < ROWS; ++r) { acc0[r] = (v4f)0.0f; acc1[r] = (v4f)0.0f; }
    #pragma unroll
    for (int i = 0; i < ORDER; ++i) {
        const v4f a0 = *(const v4f*)(vn + (size_t)i * N_FEAT + c0);
        const v4f a1 = *(const v4f*)(vn + (size_t)i * N_FEAT + c1);
        #pragma unroll
        for (int r = 0; r < ROWS; ++r) {
            acc0[r] += c[r][i] * a0;
            acc1[r] += c[r][i] * a1;
        }
    }

    const v4f d0 = *(const v4f*)(d + c0);
    const v4f d1 = *(const v4f*)(d + c1);
    const v4f b0 = *(const v4f*)(bias + c0);
    const v4f b1 = *(const v4f*)(bias + c1);
    #pragma unroll
    for (int r = 0; r < ROWS; ++r) {
        v4f o0 = (x0[r] - acc0[r]) * d0 + b0;
        v4f o1 = (x1[r] - acc1[r]) * d1 + b1;
        __builtin_nontemporal_store(o0, (v4f*)(y + base + (size_t)r * N_FEAT + c0));
        __builtin_nontemporal_store(o1, (v4f*)(y + base + (size_t)r * N_FEAT + c1));
    }
}

// ---- fallback fused apply (r5) if workspace is too small for cbuf ---------
__global__ __launch_bounds__(BLOCK, 3) void orth_apply_kernel(
    const float* __restrict__ x, const float* __restrict__ vn,
    const float* __restrict__ Tm, const float* __restrict__ d,
    const float* __restrict__ bias, float* __restrict__ y) {
    const int tid = threadIdx.x;
    const int lane = tid & 63;
    const size_t base = (size_t)blockIdx.x * ROWS * N_FEAT;
    const int c0 = tid * 4;
    const int c1 = 1024 + tid * 4;

    __shared__ float Sf[NVAL];
    if (tid < NVAL) Sf[tid] = 0.0f;
    __syncthreads();

    v4f a0[ORDER], a1[ORDER];
    #pragma unroll
    for (int i = 0; i < ORDER; ++i) {
        a0[i] = *(const v4f*)(vn + (size_t)i * N_FEAT + c0);
        a1[i] = *(const v4f*)(vn + (size_t)i * N_FEAT + c1);
    }
    v4f z0[ROWS], z1[ROWS];
    #pragma unroll
    for (int r = 0; r < ROWS; ++r) {
        z0[r] = __builtin_nontemporal_load((const v4f*)(x + base + (size_t)r * N_FEAT + c0));
        z1[r] = __builtin_nontemporal_load((const v4f*)(x + base + (size_t)r * N_FEAT + c1));
    }

    float s[NVAL];
    #pragma unroll
    for (int i = 0; i < ORDER; ++i)
        #pragma unroll
        for (int r = 0; r < ROWS; ++r)
            s[r * ORDER + i] = dot4(z0[r], a0[i]) + dot4(z1[r], a1[i]);

    #pragma unroll
    for (int step = 0; step < 5; ++step) {
        const int m = 1 << step;
        const int n = NVAL >> step;
        #pragma unroll
        for (int j = 0; j < n / 2; ++j) {
            const float a = s[2 * j], b = s[2 * j + 1];
            const float keep = (lane & m) ? b : a;
            const float send = (lane & m) ? a : b;
            s[j] = keep + __shfl_xor(send, m, 64);
        }
    }
    atomicAdd(&Sf[lane & (NVAL - 1)], s[0]);
    __syncthreads();

    float c[ROWS][ORDER];
    #pragma unroll
    for (int i = 0; i < ORDER; ++i)
        #pragma unroll
        for (int r = 0; r < ROWS; ++r) {
            float acc = 0.0f;
            #pragma unroll
            for (int j = 0; j <= i; ++j)
                acc += Sf[r * ORDER + j] * Tm[j * ORDER + i];
            c[r][i] = acc;
        }

    #pragma unroll
    for (int i = 0; i < ORDER; ++i)
        #pragma unroll
        for (int r = 0; r < ROWS; ++r) {
            z0[r] -= c[r][i] * a0[i];
            z1[r] -= c[r][i] * a1[i];
        }

    const v4f d0 = *(const v4f*)(d + c0);
    const v4f d1 = *(const v4f*)(d + c1);
    const v4f b0 = *(const v4f*)(bias + c0);
    const v4f b1 = *(const v4f*)(bias + c1);
    #pragma unroll
    for (int r = 0; r < ROWS; ++r) {
        v4f o0 = z0[r] * d0 + b0;
        v4f o1 = z1[r] * d1 + b1;
        __builtin_nontemporal_store(o0, (v4f*)(y + base + (size_t)r * N_FEAT + c0));
        __builtin_nontemporal_store(o1, (v4f*)(y + base + (size_t)r * N_FEAT + c1));
    }
}

extern "C" void kernel_launch(void* const* d_in, const int* in_sizes, int n_in,
                              void* d_out, int out_size, void* d_ws, size_t ws_size,
                              hipStream_t stream) {
    const float* x    = (const float*)d_in[0];  // [8192, 2048]
    const float* v    = (const float*)d_in[1];  // [8, 2048]
    const float* d    = (const float*)d_in[2];  // [2048]
    const float* bias = (const float*)d_in[3];  // [2048]
    float* y  = (float*)d_out;                  // [8192, 2048]
    float* vn = (float*)d_ws;                   // [8, 2048]
    float* Tm = vn + ORDER * N_FEAT;            // [8, 8]
    float* cbuf = Tm + ORDER * ORDER;           // [8192, 8]

    const size_t need =
        (size_t)(ORDER * N_FEAT + ORDER * ORDER + BATCH * ORDER) * sizeof(float);

    prep_kernel<<<1, BLOCK, 0, stream>>>(v, vn, Tm);
    if (ws_size >= need) {
        proj_kernel<<<BATCH / ROWS, BLOCK, 0, stream>>>(x, vn, Tm, cbuf);
        finish_kernel<<<BATCH / ROWS, BLOCK, 0, stream>>>(x, vn, cbuf, d, bias, y);
    } else {
        orth_apply_kernel<<<BATCH / ROWS, BLOCK, 0, stream>>>(x, vn, Tm, d, bias, y);
    }
}

// Round 7
// 132.943 us; speedup vs baseline: 1.1979x; 1.0235x over previous
//
#include <hip/hip_runtime.h>

#define N_FEAT 2048
#define ORDER 8
#define BATCH 8192
#define BLOCK 256
#define ROWS 4          // batch rows per group
#define NPAIR 28        // ORDER*(ORDER-1)/2
#define NVAL 32         // ROWS*ORDER reduction values per group
#define NBLOCK 512      // persistent blocks (2/CU)
#define GROUPS (BATCH / ROWS / NBLOCK)   // 4 groups per block

typedef float v4f __attribute__((ext_vector_type(4)));

__device__ __forceinline__ float dot4(v4f a, v4f b) {
    return a.x * b.x + a.y * b.y + a.z * b.z + a.w * b.w;
}

// ---- prep (1 block): normalize v -> vn, build compact-WY T (8x8) ----------
// H0*H1*...*H7 = I - V T V^T ; T_{k+1} = [[T_k, -2 T_k g],[0,2]], g_j = vj.vk
__global__ __launch_bounds__(BLOCK) void prep_kernel(
    const float* __restrict__ v, float* __restrict__ vn,
    float* __restrict__ Tm) {
    const int tid = threadIdx.x;
    const int lane = tid & 63, wid = tid >> 6;

    v4f a0[ORDER], a1[ORDER];
    #pragma unroll
    for (int i = 0; i < ORDER; ++i) {
        a0[i] = *(const v4f*)(v + (size_t)i * N_FEAT + tid * 4);
        a1[i] = *(const v4f*)(v + (size_t)i * N_FEAT + 1024 + tid * 4);
    }
    float ss[ORDER];
    #pragma unroll
    for (int i = 0; i < ORDER; ++i)
        ss[i] = dot4(a0[i], a0[i]) + dot4(a1[i], a1[i]);
    #pragma unroll
    for (int o = 32; o > 0; o >>= 1)
        #pragma unroll
        for (int i = 0; i < ORDER; ++i) ss[i] += __shfl_down(ss[i], o, 64);

    __shared__ float red[4][ORDER];
    __shared__ float gred[4][NPAIR];
    if (lane == 0) {
        #pragma unroll
        for (int i = 0; i < ORDER; ++i) red[wid][i] = ss[i];
    }
    __syncthreads();
    #pragma unroll
    for (int i = 0; i < ORDER; ++i) {
        const float inv = 1.0f / sqrtf(red[0][i] + red[1][i] + red[2][i] + red[3][i]);
        a0[i] *= inv; a1[i] *= inv;
        *(v4f*)(vn + (size_t)i * N_FEAT + tid * 4) = a0[i];
        *(v4f*)(vn + (size_t)i * N_FEAT + 1024 + tid * 4) = a1[i];
    }

    float gp[NPAIR];
    {
        int idx = 0;
        #pragma unroll
        for (int j = 0; j < ORDER; ++j)
            #pragma unroll
            for (int k = j + 1; k < ORDER; ++k)
                gp[idx++] = dot4(a0[j], a0[k]) + dot4(a1[j], a1[k]);
    }
    #pragma unroll
    for (int o = 32; o > 0; o >>= 1)
        #pragma unroll
        for (int q = 0; q < NPAIR; ++q) gp[q] += __shfl_down(gp[q], o, 64);
    if (lane == 0) {
        #pragma unroll
        for (int q = 0; q < NPAIR; ++q) gred[wid][q] = gp[q];
    }
    __syncthreads();

    if (tid == 0) {
        float G[ORDER][ORDER];
        {
            int idx = 0;
            #pragma unroll
            for (int j = 0; j < ORDER; ++j)
                #pragma unroll
                for (int k = j + 1; k < ORDER; ++k) {
                    G[j][k] = gred[0][idx] + gred[1][idx] + gred[2][idx] + gred[3][idx];
                    ++idx;
                }
        }
        float T[ORDER][ORDER];
        #pragma unroll
        for (int j = 0; j < ORDER; ++j)
            #pragma unroll
            for (int k = 0; k < ORDER; ++k) T[j][k] = 0.0f;
        T[0][0] = 2.0f;
        #pragma unroll
        for (int k = 1; k < ORDER; ++k) {
            #pragma unroll
            for (int j = 0; j < k; ++j) {
                float s = 0.0f;
                #pragma unroll
                for (int m = j; m < k; ++m) s += T[j][m] * G[m][k];
                T[j][k] = -2.0f * s;
            }
            T[k][k] = 2.0f;
        }
        #pragma unroll
        for (int j = 0; j < ORDER; ++j)
            #pragma unroll
            for (int k = 0; k < ORDER; ++k)
                Tm[j * ORDER + k] = T[j][k];
    }
}

// ---- apply: y = (x - (x V) T V^T) * d + bias -------------------------------
// PERSISTENT, software-pipelined: 512 blocks x 4 groups. Per group, the next
// group's x loads are issued BEFORE computing the current group, so every
// wave always has ~8KB of independent loads in flight under its compute —
// attacks the wave-lifetime latency serialization all one-shot variants hit.
// vn/d/bias/T live in registers for the whole kernel (zero reloads).
// Combine: atomic-free per-wave slots, double-buffered, ONE barrier/group.
__global__ __launch_bounds__(BLOCK) void orth_apply_kernel(
    const float* __restrict__ x, const float* __restrict__ vn,
    const float* __restrict__ Tm, const float* __restrict__ d,
    const float* __restrict__ bias, float* __restrict__ y) {
    const int tid = threadIdx.x;
    const int lane = tid & 63, wid = tid >> 6;
    const int c0 = tid * 4;
    const int c1 = 1024 + tid * 4;

    __shared__ float Sf[2][4][NVAL];

    // Persistent operands (loaded once per wave lifetime).
    v4f a0[ORDER], a1[ORDER];
    #pragma unroll
    for (int i = 0; i < ORDER; ++i) {
        a0[i] = *(const v4f*)(vn + (size_t)i * N_FEAT + c0);
        a1[i] = *(const v4f*)(vn + (size_t)i * N_FEAT + c1);
    }
    const v4f dv0 = *(const v4f*)(d + c0);
    const v4f dv1 = *(const v4f*)(d + c1);
    const v4f bv0 = *(const v4f*)(bias + c0);
    const v4f bv1 = *(const v4f*)(bias + c1);
    // T upper triangle -> SGPRs (wave-uniform addresses).
    float Tu[ORDER][ORDER];
    #pragma unroll
    for (int j = 0; j < ORDER; ++j)
        #pragma unroll
        for (int i = j; i < ORDER; ++i)
            Tu[j][i] = Tm[j * ORDER + i];

    // Prologue: load group 0.
    size_t base = (size_t)blockIdx.x * ROWS * N_FEAT;
    v4f zc0[ROWS], zc1[ROWS];
    #pragma unroll
    for (int r = 0; r < ROWS; ++r) {
        zc0[r] = __builtin_nontemporal_load((const v4f*)(x + base + (size_t)r * N_FEAT + c0));
        zc1[r] = __builtin_nontemporal_load((const v4f*)(x + base + (size_t)r * N_FEAT + c1));
    }

    #pragma unroll
    for (int t = 0; t < GROUPS; ++t) {
        // Prefetch group t+1 (independent loads in flight under the compute).
        const size_t nbase =
            (size_t)(blockIdx.x + (size_t)(t + 1) * NBLOCK) * ROWS * N_FEAT;
        v4f zn0[ROWS], zn1[ROWS];
        if (t + 1 < GROUPS) {
            #pragma unroll
            for (int r = 0; r < ROWS; ++r) {
                zn0[r] = __builtin_nontemporal_load((const v4f*)(x + nbase + (size_t)r * N_FEAT + c0));
                zn1[r] = __builtin_nontemporal_load((const v4f*)(x + nbase + (size_t)r * N_FEAT + c1));
            }
        }

        // 32 projections for the current group.
        float s[NVAL];
        #pragma unroll
        for (int i = 0; i < ORDER; ++i)
            #pragma unroll
            for (int r = 0; r < ROWS; ++r)
                s[r * ORDER + i] = dot4(zc0[r], a0[i]) + dot4(zc1[r], a1[i]);

        // Packing reduction (r5-verified): lane l ends with the 32-lane
        // partial of value l&31; one more xor-32 merges the halves so ALL
        // lanes hold the full wave-sum of value lane&31.
        #pragma unroll
        for (int step = 0; step < 5; ++step) {
            const int m = 1 << step;
            const int n = NVAL >> step;
            #pragma unroll
            for (int j = 0; j < n / 2; ++j) {
                const float a = s[2 * j], b = s[2 * j + 1];
                const float keep = (lane & m) ? b : a;
                const float send = (lane & m) ? a : b;
                s[j] = keep + __shfl_xor(send, m, 64);
            }
        }
        const float full = s[0] + __shfl_xor(s[0], 32, 64);

        // Atomic-free cross-wave combine: per-wave slot, parity buffer.
        const int buf = t & 1;
        if (lane < 32) Sf[buf][wid][lane] = full;
        __syncthreads();   // the one barrier per group

        const v4f* S4 = (const v4f*)&Sf[buf][0][0];   // [4 wids][8 v4f]
        v4f P[NVAL / 4];
        #pragma unroll
        for (int k = 0; k < NVAL / 4; ++k)
            P[k] = (S4[0 * 8 + k] + S4[1 * 8 + k]) + (S4[2 * 8 + k] + S4[3 * 8 + k]);
        #define PV(r, j) (P[((r) * ORDER + (j)) >> 2][((r) * ORDER + (j)) & 3])

        // c = p @ T (upper-triangular, all-SGPR T).
        float c[ROWS][ORDER];
        #pragma unroll
        for (int i = 0; i < ORDER; ++i)
            #pragma unroll
            for (int r = 0; r < ROWS; ++r) {
                float acc = 0.0f;
                #pragma unroll
                for (int j = 0; j <= i; ++j)
                    acc += PV(r, j) * Tu[j][i];
                c[r][i] = acc;
            }

        // Update + epilogue + nt store (r4: plain stores cost +45MB HBM).
        #pragma unroll
        for (int r = 0; r < ROWS; ++r) {
            v4f o0 = zc0[r], o1 = zc1[r];
            #pragma unroll
            for (int i = 0; i < ORDER; ++i) {
                o0 -= c[r][i] * a0[i];
                o1 -= c[r][i] * a1[i];
            }
            o0 = o0 * dv0 + bv0;
            o1 = o1 * dv1 + bv1;
            __builtin_nontemporal_store(o0, (v4f*)(y + base + (size_t)r * N_FEAT + c0));
            __builtin_nontemporal_store(o1, (v4f*)(y + base + (size_t)r * N_FEAT + c1));
        }

        // Rotate pipeline.
        if (t + 1 < GROUPS) {
            base = nbase;
            #pragma unroll
            for (int r = 0; r < ROWS; ++r) { zc0[r] = zn0[r]; zc1[r] = zn1[r]; }
        }
    }
}

extern "C" void kernel_launch(void* const* d_in, const int* in_sizes, int n_in,
                              void* d_out, int out_size, void* d_ws, size_t ws_size,
                              hipStream_t stream) {
    const float* x    = (const float*)d_in[0];  // [8192, 2048]
    const float* v    = (const float*)d_in[1];  // [8, 2048]
    const float* d    = (const float*)d_in[2];  // [2048]
    const float* bias = (const float*)d_in[3];  // [2048]
    float* y  = (float*)d_out;                  // [8192, 2048]
    float* vn = (float*)d_ws;                   // [8, 2048]
    float* Tm = vn + ORDER * N_FEAT;            // [8, 8]

    prep_kernel<<<1, BLOCK, 0, stream>>>(v, vn, Tm);
    orth_apply_kernel<<<NBLOCK, BLOCK, 0, stream>>>(x, vn, Tm, d, bias, y);
}